// Round 5
// baseline (471.833 us; speedup 1.0000x reference)
//
#include <hip/hip_runtime.h>
#include <cfloat>

// Problem constants
#define T_TOTAL 32768   // 32*32*32 spatial positions
#define DIM 64          // embedding dim
#define KCODES 1024     // num embeddings

// INSTRUMENTATION ROUND: vq_main_kernel runs its entire (idempotent) body
// TWICE so its dispatch exceeds the ~200us fill dispatches and surfaces in
// the rocprof top-5 — first-ever counters for main. Atomics guarded to iter 0.

// d_out flat layout (fp32 elements), reference return order:
//   quantized_out [32,64,32,32] = 2097152
//   loss (1), perplexity (1)
//   encodings [32768,1024] = 33554432
//   distances [32768,1024] = 33554432
static constexpr long long OFF_Q    = 0;
static constexpr long long OFF_LOSS = 2097152;
static constexpr long long OFF_PERP = 2097153;
static constexpr long long OFF_ENC  = 2097154;            // float idx % 4 == 2 -> region 8B aligned; enc+2 is 16B aligned
static constexpr long long OFF_DIST = 2097154LL + 33554432LL; // same alignment situation

// ws layout: [0,4096) int counts[1024]; [4096,8192) float ww[1024];
//            [8192,8196) float lossSum; [12288, 12288+256K) float WT[64][1024]

#define AS1 __attribute__((address_space(1)))
#define AS3 __attribute__((address_space(3)))

// Direct global->LDS DMA, 16B per lane. LDS dest must be wave-uniform base;
// HW writes lane i's 16B at base + i*16. Global src is per-lane.
__device__ __forceinline__ void gld16(const float* g, float* l) {
    __builtin_amdgcn_global_load_lds((const AS1 unsigned int*)g,
                                     (AS3 unsigned int*)l, 16, 0, 0);
}

// Counted-vmcnt phase barrier: wait until <=N VMEM ops outstanding (in-order
// FIFO -> guarantees everything older than the N youngest has retired), then
// raw workgroup barrier. sched_barrier(0) pins code motion across it.
#define PHASE_SYNC(N) do {                                        \
    asm volatile("s_waitcnt vmcnt(" #N ")" ::: "memory");         \
    __builtin_amdgcn_s_barrier();                                 \
    __builtin_amdgcn_sched_barrier(0);                            \
} while (0)

// ---------------------------------------------------------------------------
// Prep: ||w_k||^2 (blocks 0..255) + W transpose WT[n][k] (blocks 256..319)
//     + enc row-boundary zero patches (blocks 320..383)
//     + counts/lossSum zeroing (block 384; replaces the hipMemsetAsync dispatch).
__global__ __launch_bounds__(256) void vq_prep_kernel(const float* __restrict__ W,
                                                      float* __restrict__ ww,
                                                      float* __restrict__ WT,
                                                      float* __restrict__ out,
                                                      int* __restrict__ counts,
                                                      float* __restrict__ lossSum) {
    const int tid = threadIdx.x;
    const int b   = blockIdx.x;
    if (b < 256) {
        const int lane = tid & 63;
        const int code = b * 4 + (tid >> 6);
        float v = W[code * DIM + lane];
        float s = v * v;
        #pragma unroll
        for (int off = 32; off > 0; off >>= 1)
            s += __shfl_down(s, off, 64);
        if (lane == 0) ww[code] = s;
    } else if (b < 320) {
        const int n = b - 256;            // 0..63
        #pragma unroll
        for (int i = 0; i < 4; ++i) {
            int k = i * 256 + tid;
            WT[n * KCODES + k] = W[k * DIM + n];
        }
    } else if (b < 384) {
        // enc boundary patches: floats {0,1} and {1022,1023} of every row
        // (main's in-loop streaming covers the 16B-aligned interior [2,1022)).
        float* __restrict__ enc = out + OFF_ENC;
        const float2 z2 = make_float2(0.f, 0.f);
        const int r0 = (b - 320) * 512 + tid * 2;   // 2 rows per thread
        const long long rb = (long long)r0 * KCODES;
        *(float2*)&enc[rb]               = z2;
        *(float2*)&enc[rb + 1022]        = z2;
        *(float2*)&enc[rb + 1024]        = z2;
        *(float2*)&enc[rb + 1024 + 1022] = z2;
    } else {
        #pragma unroll
        for (int i = 0; i < 4; ++i) counts[i * 256 + tid] = 0;
        if (tid == 0) lossSum[0] = 0.f;
    }
}

// ---------------------------------------------------------------------------
// Main fused kernel: distances GEMM + argmin + one-hot + gather + loss partial.
// 512 blocks x 256 threads; each block owns 64 consecutive flat rows t.
// 16 pipelined phases (2 code-chunks x 8 n-slices of 8), double-buffered LDS
// staged via global_load_lds, counted-vmcnt barriers (stores never drained
// in-loop). THIS ROUND: body executed twice (idempotent) for profiling.
__global__ __launch_bounds__(256, 2) void vq_main_kernel(const float* __restrict__ lat,
                                                         const float* __restrict__ W,
                                                         const float* __restrict__ ww,
                                                         const float* __restrict__ WT,
                                                         float* __restrict__ out,
                                                         int* __restrict__ counts,
                                                         float* __restrict__ lossSum) {
    __shared__ float xT[64 * 64];      // [n][tl] 16 KB — persistent across kernel
    __shared__ float wS[2][8 * 512];   // [nl][k] 16 KB x2 double buffer; reused for red/qS
    __shared__ float wwS[KCODES];      // ||w||^2, 4 KB
    __shared__ float xx[64];           // ||x_row||^2
    __shared__ int   selIdx[64];

    const int tid = threadIdx.x;
    const int tx  = tid & 31;          // 32 k-threads x 16 codes = 512-code chunk
    const int ty  = tid >> 5;          // 8 row-groups
    const int t0  = blockIdx.x * 64;
    // flat row t maps to latent addr b*65536 + n*1024 + (j*32+d); for a 64-row block
    // the (j*32+d) part is contiguous: base + n*1024 + tl
    const long long base = (long long)(t0 >> 10) * 65536 + (long long)(t0 & 1023);
    const int wbase = (tid & 192) * 4; // wave-uniform float-offset component of LDS dest

    for (int iter = 0; iter < 2; ++iter) {   // x2 for profiling; iter 1 idempotent

    // ---- prologue: DMA x tile (16 KB) + first WT slice (16 KB) straight into LDS
    #pragma unroll
    for (int i = 0; i < 4; ++i) {
        const int e = i * 256 + tid;   // f4 index in [0,1024)
        gld16(&lat[base + (long long)(e >> 4) * 1024 + (e & 15) * 4],
              &xT[i * 1024 + wbase]);
    }
    #pragma unroll
    for (int i = 0; i < 4; ++i) {
        const int e = i * 256 + tid;   // f4 index in [0,1024): nl = e>>7, k4 = e&127
        gld16(&WT[(e >> 7) * KCODES + (e & 127) * 4],
              &wS[0][i * 1024 + wbase]);
    }
    *(float4*)&wwS[tid * 4] = *(const float4*)&ww[tid * 4];
    __syncthreads();                   // full drain: vmcnt=0 entering the loop

    // ||x||^2 per row (wave 0 only; published by the phase-0 end barrier,
    // first consumed at phase 7)
    if (tid < 64) {
        float s = 0.f;
        #pragma unroll 8
        for (int n = 0; n < 64; ++n) {
            float v = xT[n * 64 + tid];
            s = fmaf(v, v, s);
        }
        xx[tid] = s;
    }

    float minV[8];
    int   minI[8];
    #pragma unroll
    for (int r = 0; r < 8; ++r) { minV[r] = FLT_MAX; minI[r] = 0; }

    float acc[8][16];
    float* __restrict__ distOut = out + OFF_DIST;
    float* __restrict__ enc     = out + OFF_ENC;
    const float4 z4 = make_float4(0.f, 0.f, 0.f, 0.f);
    const int tcl = (tid < 255 ? tid : 254) * 4;   // tail thread duplicates slot 254
                                                   // (same-address zero store, benign)
                                                   // -> uniform 4 stores per thread

    for (int p = 0; p < 16; ++p) {     // phase p = c*8 + q: codes [c*512,(c+1)*512), dims [q*8,q*8+8)
        const int c   = p >> 3;
        const int q   = p & 7;
        const int buf = p & 1;

        // ---- (1) prefetch next phase's WT slice — the ONLY loads this phase;
        //      issued first so they are the OLDEST VMEM ops at the barrier.
        if (p < 15) {
            const int pn = p + 1;
            const float* srcb = WT + (pn & 7) * (8 * KCODES) + (pn >> 3) * 512;
            float* dstb = &wS[pn & 1][0];
            #pragma unroll
            for (int i = 0; i < 4; ++i) {
                const int e = i * 256 + tid;
                gld16(&srcb[(e >> 7) * KCODES + (e & 127) * 4],
                      &dstb[i * 1024 + wbase]);
            }
        }
        asm volatile("" ::: "memory"); // pin: all loads precede all stores

        // ---- (2) enc zero-fill interior [2,1022) for rows p*4..p*4+3
        //      (uniform 4 float4 stores/thread; boundaries written by prep)
        {
            float* pz = enc + (long long)(t0 + p * 4) * KCODES + 2;
            *(float4*)(pz + tcl)        = z4;
            *(float4*)(pz + 1024 + tcl) = z4;
            *(float4*)(pz + 2048 + tcl) = z4;
            *(float4*)(pz + 3072 + tcl) = z4;
        }

        if (q == 0) {
            #pragma unroll
            for (int r = 0; r < 8; ++r)
                #pragma unroll
                for (int k = 0; k < 16; ++k) acc[r][k] = 0.f;
        }

        // ---- (3) 8x16 register-tiled fp32 GEMM over this 8-dim slice
        #pragma unroll 2
        for (int nn = 0; nn < 8; ++nn) {
            const float* xrow = &xT[(q * 8 + nn) * 64];
            const float* wrow = &wS[buf][nn * 512];
            float4 a0 = *(const float4*)&xrow[ty * 4];        // broadcast (free)
            float4 a1 = *(const float4*)&xrow[32 + ty * 4];
            float4 b0 = *(const float4*)&wrow[tx * 4];        // contiguous b128
            float4 b1 = *(const float4*)&wrow[128 + tx * 4];
            float4 b2 = *(const float4*)&wrow[256 + tx * 4];
            float4 b3 = *(const float4*)&wrow[384 + tx * 4];
            float ar[8]  = {a0.x, a0.y, a0.z, a0.w, a1.x, a1.y, a1.z, a1.w};
            float br[16] = {b0.x, b0.y, b0.z, b0.w, b1.x, b1.y, b1.z, b1.w,
                            b2.x, b2.y, b2.z, b2.w, b3.x, b3.y, b3.z, b3.w};
            #pragma unroll
            for (int r = 0; r < 8; ++r)
                #pragma unroll
                for (int k = 0; k < 16; ++k)
                    acc[r][k] = fmaf(ar[r], br[k], acc[r][k]);
        }

        // ---- (4) chunk complete: distances out + running argmin
        // thread's codes: k = c*512 + qq*128 + tx*4 + j — ascending scan order,
        // strict < keeps the first (np.argmin tie semantics)
        if (q == 7) {
            const int kb = c * 512 + tx * 4;
            float wr[16];
            #pragma unroll
            for (int qq = 0; qq < 4; ++qq) {
                float4 w4 = *(const float4*)&wwS[kb + qq * 128];
                wr[qq*4+0] = w4.x; wr[qq*4+1] = w4.y; wr[qq*4+2] = w4.z; wr[qq*4+3] = w4.w;
            }
            #pragma unroll
            for (int r = 0; r < 8; ++r) {
                const int row = (r >> 2) * 32 + ty * 4 + (r & 3);
                const float xxr = xx[row];
                const long long ro = (long long)(t0 + row) * KCODES + kb;
                #pragma unroll
                for (int qq = 0; qq < 4; ++qq) {
                    float d0 = (xxr + wr[qq*4+0]) - 2.f * acc[r][qq*4+0];
                    float d1 = (xxr + wr[qq*4+1]) - 2.f * acc[r][qq*4+1];
                    float d2 = (xxr + wr[qq*4+2]) - 2.f * acc[r][qq*4+2];
                    float d3 = (xxr + wr[qq*4+3]) - 2.f * acc[r][qq*4+3];
                    const int k0 = kb + qq * 128;
                    if (d0 < minV[r]) { minV[r] = d0; minI[r] = k0;     }
                    if (d1 < minV[r]) { minV[r] = d1; minI[r] = k0 + 1; }
                    if (d2 < minV[r]) { minV[r] = d2; minI[r] = k0 + 2; }
                    if (d3 < minV[r]) { minV[r] = d3; minI[r] = k0 + 3; }
                    *(float2*)&distOut[ro + qq * 128]     = make_float2(d0, d1);
                    *(float2*)&distOut[ro + qq * 128 + 2] = make_float2(d2, d3);
                }
            }
        }

        // ---- (5) counted-vmcnt barrier: wait ONLY for this phase's 4 prefetch
        // loads (oldest in the FIFO); leave the store burst in flight.
        if (q == 7) PHASE_SYNC(63);
        else        PHASE_SYNC(4);
    }

    // ---- cross-thread argmin reduction (32 candidates per row), alias wS
    float* wSf  = &wS[0][0];
    float* redV = wSf;                 // [64][33] padded -> conflict-free scan
    int*   redI = (int*)(wSf + 64 * 33);
    #pragma unroll
    for (int r = 0; r < 8; ++r) {
        const int row = (r >> 2) * 32 + ty * 4 + (r & 3);
        redV[row * 33 + tx] = minV[r];
        redI[row * 33 + tx] = minI[r];
    }
    __syncthreads();                   // FULL drain: retires all in-flight stores
                                       // (required before the enc 1.0 fixups below)
    if (tid < 64) {
        float best = redV[tid * 33];
        int   bi   = redI[tid * 33];
        #pragma unroll
        for (int s = 1; s < 32; ++s) {
            float v  = redV[tid * 33 + s];
            int   i2 = redI[tid * 33 + s];
            if (v < best || (v == best && i2 < bi)) { best = v; bi = i2; }
        }
        selIdx[tid] = bi;
        if (iter == 0) atomicAdd(&counts[bi], 1);   // guard: no double-count
    }
    __syncthreads();

    // ---- gather selected codebook rows into LDS (coalesced), stride 65 kills conflicts
    float* qS = wSf;  // reuse (scan done)
    #pragma unroll
    for (int i = 0; i < 16; ++i) {
        int e   = i * 256 + tid;
        int row = e >> 6;
        int n   = e & 63;
        qS[row * 65 + n] = W[selIdx[row] * DIM + n];
    }
    __syncthreads();

    // ---- quantized_out (float4, 16B aligned) + loss partial
    float ls = 0.f;
    #pragma unroll
    for (int i = 0; i < 4; ++i) {
        int e2  = i * 256 + tid;       // [0,1024) float4s
        int n   = e2 >> 4;
        int tl0 = (e2 & 15) * 4;
        float q0 = qS[(tl0 + 0) * 65 + n];
        float q1 = qS[(tl0 + 1) * 65 + n];
        float q2 = qS[(tl0 + 2) * 65 + n];
        float q3 = qS[(tl0 + 3) * 65 + n];
        float x0 = xT[n * 64 + tl0 + 0];
        float x1 = xT[n * 64 + tl0 + 1];
        float x2 = xT[n * 64 + tl0 + 2];
        float x3 = xT[n * 64 + tl0 + 3];
        *(float4*)&out[OFF_Q + base + (long long)n * 1024 + tl0] = make_float4(q0, q1, q2, q3);
        float e0 = q0 - x0; ls = fmaf(e0, e0, ls);
        float e1 = q1 - x1; ls = fmaf(e1, e1, ls);
        float e2d = q2 - x2; ls = fmaf(e2d, e2d, ls);
        float e3 = q3 - x3; ls = fmaf(e3, e3, ls);
    }
    #pragma unroll
    for (int off = 32; off > 0; off >>= 1)
        ls += __shfl_down(ls, off, 64);
    if ((tid & 63) == 0 && iter == 0) atomicAdd(lossSum, ls);   // guard

    // ---- one-hot fix-up: zeros (interior from the loop, boundaries from prep)
    // drained by the epilogue's first __syncthreads; 1.0 per row completes enc.
    // (iter 1 re-zeros then re-writes the same 1.0 — ordered by the same barriers)
    if (tid < 64)
        enc[(long long)(t0 + tid) * KCODES + selIdx[tid]] = 1.f;

    __syncthreads();                   // iter boundary: selIdx/qS/xT reuse safety
    }  // iter
}

// ---------------------------------------------------------------------------
// Finalize: perplexity from histogram, loss from accumulated SSE.
__global__ __launch_bounds__(1024) void vq_finalize_kernel(const int* __restrict__ counts,
                                                           const float* __restrict__ lossSum,
                                                           float* __restrict__ out) {
    __shared__ float red[16];
    const int tid = threadIdx.x;
    float p = (float)counts[tid] * (1.0f / 32768.0f);   // exact (pow2 divisor)
    float term = p * logf(p + 1e-10f);
    #pragma unroll
    for (int off = 32; off > 0; off >>= 1)
        term += __shfl_down(term, off, 64);
    if ((tid & 63) == 0) red[tid >> 6] = term;
    __syncthreads();
    if (tid == 0) {
        float s = 0.f;
        #pragma unroll
        for (int i = 0; i < 16; ++i) s += red[i];
        out[OFF_PERP] = expf(-s);
        out[OFF_LOSS] = 0.25f * lossSum[0] * (1.0f / 2097152.0f);  // COMMIT_COST * mean SSE
    }
}

// ---------------------------------------------------------------------------
extern "C" void kernel_launch(void* const* d_in, const int* in_sizes, int n_in,
                              void* d_out, int out_size, void* d_ws, size_t ws_size,
                              hipStream_t stream) {
    (void)in_sizes; (void)n_in; (void)out_size; (void)ws_size;
    const float* lat = (const float*)d_in[0];   // [32,64,32,32]
    const float* W   = (const float*)d_in[1];   // [1024,64]
    float* out = (float*)d_out;

    int*   counts  = (int*)d_ws;
    float* ww      = (float*)((char*)d_ws + 4096);
    float* lossSum = (float*)((char*)d_ws + 8192);
    float* WT      = (float*)((char*)d_ws + 12288);   // 64x1024 fp32 = 256 KB

    // prep zeroes counts/lossSum (block 384) — no hipMemsetAsync dispatch needed
    vq_prep_kernel<<<385, 256, 0, stream>>>(W, ww, WT, out, counts, lossSum);
    vq_main_kernel<<<512, 256, 0, stream>>>(lat, W, ww, WT, out, counts, lossSum);
    vq_finalize_kernel<<<1, 1024, 0, stream>>>(counts, lossSum, out);
}

// Round 6
// 401.747 us; speedup vs baseline: 1.1745x; 1.1745x over previous
//
#include <hip/hip_runtime.h>
#include <cfloat>

// Problem constants
#define T_TOTAL 32768   // 32*32*32 spatial positions
#define DIM 64          // embedding dim
#define KCODES 1024     // num embeddings

// d_out flat layout (fp32 elements), reference return order:
//   quantized_out [32,64,32,32] = 2097152
//   loss (1), perplexity (1)
//   encodings [32768,1024] = 33554432
//   distances [32768,1024] = 33554432
static constexpr long long OFF_Q    = 0;
static constexpr long long OFF_LOSS = 2097152;
static constexpr long long OFF_PERP = 2097153;
static constexpr long long OFF_ENC  = 2097154;            // float idx % 4 == 2 -> region 8B aligned; enc+2 is 16B aligned
static constexpr long long OFF_DIST = 2097154LL + 33554432LL; // same alignment situation

// ws layout: [0,4096) int counts[1024]; [4096,8192) float ww[1024];
//            [8192,8196) float lossSum; [12288, 12288+256K) float WT[64][1024]

#define AS1 __attribute__((address_space(1)))
#define AS3 __attribute__((address_space(3)))

// Direct global->LDS DMA, 16B per lane. LDS dest must be wave-uniform base;
// HW writes lane i's 16B at base + i*16. Global src is per-lane.
__device__ __forceinline__ void gld16(const float* g, float* l) {
    __builtin_amdgcn_global_load_lds((const AS1 unsigned int*)g,
                                     (AS3 unsigned int*)l, 16, 0, 0);
}

// Counted-vmcnt phase barrier: wait until <=N VMEM ops outstanding (in-order
// FIFO -> guarantees everything older than the N youngest has retired), then
// raw workgroup barrier. sched_barrier(0) pins code motion across it.
#define PHASE_SYNC(N) do {                                        \
    asm volatile("s_waitcnt vmcnt(" #N ")" ::: "memory");         \
    __builtin_amdgcn_s_barrier();                                 \
    __builtin_amdgcn_sched_barrier(0);                            \
} while (0)

// ---------------------------------------------------------------------------
// Prep: ||w_k||^2 (blocks 0..255) + W transpose WT[n][k] (blocks 256..319)
//     + enc row-boundary zero patches (blocks 320..383)
//     + counts/lossSum zeroing (block 384).
__global__ __launch_bounds__(256) void vq_prep_kernel(const float* __restrict__ W,
                                                      float* __restrict__ ww,
                                                      float* __restrict__ WT,
                                                      float* __restrict__ out,
                                                      int* __restrict__ counts,
                                                      float* __restrict__ lossSum) {
    const int tid = threadIdx.x;
    const int b   = blockIdx.x;
    if (b < 256) {
        const int lane = tid & 63;
        const int code = b * 4 + (tid >> 6);
        float v = W[code * DIM + lane];
        float s = v * v;
        #pragma unroll
        for (int off = 32; off > 0; off >>= 1)
            s += __shfl_down(s, off, 64);
        if (lane == 0) ww[code] = s;
    } else if (b < 320) {
        const int n = b - 256;            // 0..63
        #pragma unroll
        for (int i = 0; i < 4; ++i) {
            int k = i * 256 + tid;
            WT[n * KCODES + k] = W[k * DIM + n];
        }
    } else if (b < 384) {
        // enc boundary patches: floats {0,1} and {1022,1023} of every row
        // (main's in-loop streaming covers the 16B-aligned interior [2,1022)).
        float* __restrict__ enc = out + OFF_ENC;
        const float2 z2 = make_float2(0.f, 0.f);
        const int r0 = (b - 320) * 512 + tid * 2;   // 2 rows per thread
        const long long rb = (long long)r0 * KCODES;
        *(float2*)&enc[rb]               = z2;
        *(float2*)&enc[rb + 1022]        = z2;
        *(float2*)&enc[rb + 1024]        = z2;
        *(float2*)&enc[rb + 1024 + 1022] = z2;
    } else {
        #pragma unroll
        for (int i = 0; i < 4; ++i) counts[i * 256 + tid] = 0;
        if (tid == 0) lossSum[0] = 0.f;
    }
}

// ---------------------------------------------------------------------------
// Main fused kernel. 512 blocks x 512 THREADS (8 waves); each block owns 64
// rows. Occupancy fix (R5 counters: VALUBusy 28%, conflicts ~0, occupancy
// 22.5% grid-limited at 2 waves/SIMD): 8x8 micro-tile, VGPR<=128 via
// __launch_bounds__(512,4) -> 2 blocks x 8 waves = 16 waves/CU (4/SIMD).
// Decomposition: tx = lane (64 code-threads x 8 codes = 512-code chunk),
// ty = wave (8 row-groups x 8 rows). A-fragments become wave-uniform LDS
// broadcasts (free); per-row argmin is wave-internal -> shuffle butterfly.
// 16 phases, double-buffered wS via global_load_lds, counted-vmcnt barriers.
// Per-phase VMEM issue order (uniform): 2x gld16 -> 2x enc f4 -> [q7: 32x dist f2].
__global__ __launch_bounds__(512, 4) void vq_main_kernel(const float* __restrict__ lat,
                                                         const float* __restrict__ W,
                                                         const float* __restrict__ ww,
                                                         const float* __restrict__ WT,
                                                         float* __restrict__ out,
                                                         int* __restrict__ counts,
                                                         float* __restrict__ lossSum) {
    __shared__ float xT[64 * 64];      // [n][tl] 16 KB — persistent across kernel
    __shared__ float wS[2][8 * 512];   // [nl][k] 16 KB x2 double buffer; reused for qS
    __shared__ float wwS[KCODES];      // ||w||^2, 4 KB
    __shared__ float xx[64];           // ||x_row||^2
    __shared__ int   selIdx[64];

    const int tid = threadIdx.x;       // 0..511
    const int tx  = tid & 63;          // lane within wave = code-thread
    const int ty  = tid >> 6;          // wave id = row-group
    const int t0  = blockIdx.x * 64;
    // flat row t maps to latent addr b*65536 + n*1024 + (j*32+d); for a 64-row block
    // the (j*32+d) part is contiguous: base + n*1024 + tl
    const long long base = (long long)(t0 >> 10) * 65536 + (long long)(t0 & 1023);
    const int wbase = (tid & 448) * 4; // wave-uniform float-offset component of LDS dest

    // ---- prologue: DMA x tile (16 KB) + first WT slice (16 KB) straight into LDS
    #pragma unroll
    for (int i = 0; i < 2; ++i) {
        const int e = i * 512 + tid;   // f4 index in [0,1024)
        gld16(&lat[base + (long long)(e >> 4) * 1024 + (e & 15) * 4],
              &xT[i * 2048 + wbase]);
    }
    #pragma unroll
    for (int i = 0; i < 2; ++i) {
        const int e = i * 512 + tid;   // f4 index in [0,1024): nl = e>>7, k4 = e&127
        gld16(&WT[(e >> 7) * KCODES + (e & 127) * 4],
              &wS[0][i * 2048 + wbase]);
    }
    *(float2*)&wwS[tid * 2] = *(const float2*)&ww[tid * 2];
    __syncthreads();                   // full drain: vmcnt=0 entering the loop

    // ||x||^2 per row (published by the phase-0 end barrier, consumed at phase 7)
    if (tid < 64) {
        float s = 0.f;
        #pragma unroll 8
        for (int n = 0; n < 64; ++n) {
            float v = xT[n * 64 + tid];
            s = fmaf(v, v, s);
        }
        xx[tid] = s;
    }

    float minV[8];
    int   minI[8];
    #pragma unroll
    for (int r = 0; r < 8; ++r) { minV[r] = FLT_MAX; minI[r] = 0; }

    float acc[8][8];
    float* __restrict__ distOut = out + OFF_DIST;
    float* __restrict__ enc     = out + OFF_ENC;
    const float4 z4 = make_float4(0.f, 0.f, 0.f, 0.f);

    for (int p = 0; p < 16; ++p) {     // phase p = c*8 + q: codes [c*512,(c+1)*512), dims [q*8,q*8+8)
        const int c   = p >> 3;
        const int q   = p & 7;
        const int buf = p & 1;

        // ---- (1) prefetch next phase's WT slice — the ONLY loads this phase;
        //      issued first so they are the OLDEST VMEM ops at the barrier.
        if (p < 15) {
            const int pn = p + 1;
            const float* srcb = WT + (pn & 7) * (8 * KCODES) + (pn >> 3) * 512;
            float* dstb = &wS[pn & 1][0];
            #pragma unroll
            for (int i = 0; i < 2; ++i) {
                const int e = i * 512 + tid;
                gld16(&srcb[(e >> 7) * KCODES + (e & 127) * 4],
                      &dstb[i * 2048 + wbase]);
            }
        }
        asm volatile("" ::: "memory"); // pin: all loads precede all stores

        // ---- (2) enc zero-fill interior [2,1022) for rows p*4..p*4+3
        //      (uniform 2 float4 stores/thread; boundaries written by prep)
        {
            float4* pzf = (float4*)(enc + (long long)(t0 + p * 4) * KCODES + 2); // 16B aligned
            const int rr = tid >> 7;                 // 0..3 row within group
            const int j  = tid & 127;                // f4 slot 0..127
            const int j2 = (j + 128 > 254) ? 254 : j + 128;  // clamp dup (benign)
            pzf[rr * 256 + j]  = z4;
            pzf[rr * 256 + j2] = z4;
        }

        if (q == 0) {
            #pragma unroll
            for (int r = 0; r < 8; ++r)
                #pragma unroll
                for (int k = 0; k < 8; ++k) acc[r][k] = 0.f;
        }

        // ---- (3) 8x8 register-tiled fp32 GEMM over this 8-dim slice.
        // a-reads are wave-uniform (broadcast, free); b-reads conflict-free b128.
        #pragma unroll 2
        for (int nn = 0; nn < 8; ++nn) {
            const float* xrow = &xT[(q * 8 + nn) * 64];
            const float* wrow = &wS[buf][nn * 512];
            float4 a0 = *(const float4*)&xrow[ty * 4];        // rows ty*4..+3
            float4 a1 = *(const float4*)&xrow[32 + ty * 4];   // rows 32+ty*4..+3
            float4 b0 = *(const float4*)&wrow[tx * 4];        // codes tx*4..+3
            float4 b1 = *(const float4*)&wrow[256 + tx * 4];  // codes 256+tx*4..+3
            float ar[8] = {a0.x, a0.y, a0.z, a0.w, a1.x, a1.y, a1.z, a1.w};
            float br[8] = {b0.x, b0.y, b0.z, b0.w, b1.x, b1.y, b1.z, b1.w};
            #pragma unroll
            for (int r = 0; r < 8; ++r)
                #pragma unroll
                for (int k = 0; k < 8; ++k)
                    acc[r][k] = fmaf(ar[r], br[k], acc[r][k]);
        }

        // ---- (4) chunk complete: distances out + running argmin
        // thread's codes: k = c*512 + g*256 + tx*4 + j — ascending scan order,
        // strict < keeps the first (np.argmin tie semantics)
        if (q == 7) {
            const int kb = c * 512 + tx * 4;
            float wr[8];
            {
                float4 wa = *(const float4*)&wwS[kb];
                float4 wb = *(const float4*)&wwS[kb + 256];
                wr[0]=wa.x; wr[1]=wa.y; wr[2]=wa.z; wr[3]=wa.w;
                wr[4]=wb.x; wr[5]=wb.y; wr[6]=wb.z; wr[7]=wb.w;
            }
            #pragma unroll
            for (int r = 0; r < 8; ++r) {
                const int row = (r >> 2) * 32 + ty * 4 + (r & 3);
                const float xxr = xx[row];                     // wave-uniform
                const long long ro = (long long)(t0 + row) * KCODES + kb;
                #pragma unroll
                for (int g = 0; g < 2; ++g) {
                    float d0 = (xxr + wr[g*4+0]) - 2.f * acc[r][g*4+0];
                    float d1 = (xxr + wr[g*4+1]) - 2.f * acc[r][g*4+1];
                    float d2 = (xxr + wr[g*4+2]) - 2.f * acc[r][g*4+2];
                    float d3 = (xxr + wr[g*4+3]) - 2.f * acc[r][g*4+3];
                    const int k0 = kb + g * 256;
                    if (d0 < minV[r]) { minV[r] = d0; minI[r] = k0;     }
                    if (d1 < minV[r]) { minV[r] = d1; minI[r] = k0 + 1; }
                    if (d2 < minV[r]) { minV[r] = d2; minI[r] = k0 + 2; }
                    if (d3 < minV[r]) { minV[r] = d3; minI[r] = k0 + 3; }
                    *(float2*)&distOut[ro + g * 256]     = make_float2(d0, d1);
                    *(float2*)&distOut[ro + g * 256 + 2] = make_float2(d2, d3);
                }
            }
        }

        // ---- (5) counted-vmcnt barrier: wait ONLY for this phase's 2 prefetch
        // loads (oldest in the FIFO); leave store bursts in flight.
        // normal: 2 loads + 2 enc stores -> vmcnt(2). q7: +32 dist -> vmcnt(34).
        if (q == 7) PHASE_SYNC(34);
        else        PHASE_SYNC(2);
    }

    // ---- per-row argmin: candidates for each row live entirely within one
    // wave (ty owns rows). 6-step butterfly on (val,idx); after it, all lanes
    // hold the row minimum; lane tx==r publishes row r's result.
    #pragma unroll
    for (int r = 0; r < 8; ++r) {
        float v  = minV[r];
        int   bi = minI[r];
        #pragma unroll
        for (int off = 1; off < 64; off <<= 1) {
            float v2 = __shfl_xor(v, off, 64);
            int   i2 = __shfl_xor(bi, off, 64);
            if (v2 < v || (v2 == v && i2 < bi)) { v = v2; bi = i2; }
        }
        if (tx == r) {
            const int row = (r >> 2) * 32 + ty * 4 + (r & 3);
            selIdx[row] = bi;
            atomicAdd(&counts[bi], 1);
        }
    }
    __syncthreads();                   // FULL drain (vmcnt 0): retires all enc/dist
                                       // stores (required before enc 1.0 fixups);
                                       // publishes selIdx; wS free for reuse

    // ---- gather selected codebook rows into LDS (coalesced), stride 65 kills conflicts
    float* qS = &wS[0][0];
    #pragma unroll
    for (int i = 0; i < 8; ++i) {
        int e   = i * 512 + tid;       // [0,4096)
        int row = e >> 6;
        int n   = e & 63;
        qS[row * 65 + n] = W[selIdx[row] * DIM + n];
    }
    __syncthreads();

    // ---- quantized_out (float4, 16B aligned) + loss partial
    float ls = 0.f;
    #pragma unroll
    for (int i = 0; i < 2; ++i) {
        int e2  = i * 512 + tid;       // [0,1024) float4s
        int n   = e2 >> 4;
        int tl0 = (e2 & 15) * 4;
        float q0 = qS[(tl0 + 0) * 65 + n];
        float q1 = qS[(tl0 + 1) * 65 + n];
        float q2 = qS[(tl0 + 2) * 65 + n];
        float q3 = qS[(tl0 + 3) * 65 + n];
        float x0 = xT[n * 64 + tl0 + 0];
        float x1 = xT[n * 64 + tl0 + 1];
        float x2 = xT[n * 64 + tl0 + 2];
        float x3 = xT[n * 64 + tl0 + 3];
        *(float4*)&out[OFF_Q + base + (long long)n * 1024 + tl0] = make_float4(q0, q1, q2, q3);
        float e0 = q0 - x0; ls = fmaf(e0, e0, ls);
        float e1 = q1 - x1; ls = fmaf(e1, e1, ls);
        float e2d = q2 - x2; ls = fmaf(e2d, e2d, ls);
        float e3 = q3 - x3; ls = fmaf(e3, e3, ls);
    }
    #pragma unroll
    for (int off = 32; off > 0; off >>= 1)
        ls += __shfl_down(ls, off, 64);
    if (tx == 0) atomicAdd(lossSum, ls);

    // ---- one-hot fix-up: zeros (interior from the loop, boundaries from prep)
    // are all drained by the epilogue's first __syncthreads, so a single 1.0
    // store per row completes encodings.
    if (tid < 64)
        enc[(long long)(t0 + tid) * KCODES + selIdx[tid]] = 1.f;
}

// ---------------------------------------------------------------------------
// Finalize: perplexity from histogram, loss from accumulated SSE.
__global__ __launch_bounds__(1024) void vq_finalize_kernel(const int* __restrict__ counts,
                                                           const float* __restrict__ lossSum,
                                                           float* __restrict__ out) {
    __shared__ float red[16];
    const int tid = threadIdx.x;
    float p = (float)counts[tid] * (1.0f / 32768.0f);   // exact (pow2 divisor)
    float term = p * logf(p + 1e-10f);
    #pragma unroll
    for (int off = 32; off > 0; off >>= 1)
        term += __shfl_down(term, off, 64);
    if ((tid & 63) == 0) red[tid >> 6] = term;
    __syncthreads();
    if (tid == 0) {
        float s = 0.f;
        #pragma unroll
        for (int i = 0; i < 16; ++i) s += red[i];
        out[OFF_PERP] = expf(-s);
        out[OFF_LOSS] = 0.25f * lossSum[0] * (1.0f / 2097152.0f);  // COMMIT_COST * mean SSE
    }
}

// ---------------------------------------------------------------------------
extern "C" void kernel_launch(void* const* d_in, const int* in_sizes, int n_in,
                              void* d_out, int out_size, void* d_ws, size_t ws_size,
                              hipStream_t stream) {
    (void)in_sizes; (void)n_in; (void)out_size; (void)ws_size;
    const float* lat = (const float*)d_in[0];   // [32,64,32,32]
    const float* W   = (const float*)d_in[1];   // [1024,64]
    float* out = (float*)d_out;

    int*   counts  = (int*)d_ws;
    float* ww      = (float*)((char*)d_ws + 4096);
    float* lossSum = (float*)((char*)d_ws + 8192);
    float* WT      = (float*)((char*)d_ws + 12288);   // 64x1024 fp32 = 256 KB

    // prep zeroes counts/lossSum (block 384) — no hipMemsetAsync dispatch needed
    vq_prep_kernel<<<385, 256, 0, stream>>>(W, ww, WT, out, counts, lossSum);
    vq_main_kernel<<<512, 512, 0, stream>>>(lat, W, ww, WT, out, counts, lossSum);
    vq_finalize_kernel<<<1, 1024, 0, stream>>>(counts, lossSum, out);
}

// Round 7
// 327.530 us; speedup vs baseline: 1.4406x; 1.2266x over previous
//
#include <hip/hip_runtime.h>
#include <cfloat>

// Problem constants
#define T_TOTAL 32768   // 32*32*32 spatial positions
#define DIM 64          // embedding dim
#define KCODES 1024     // num embeddings

// d_out flat layout (fp32 elements), reference return order:
//   quantized_out [32,64,32,32] = 2097152
//   loss (1), perplexity (1)
//   encodings [32768,1024] = 33554432
//   distances [32768,1024] = 33554432
static constexpr long long OFF_Q    = 0;
static constexpr long long OFF_LOSS = 2097152;
static constexpr long long OFF_PERP = 2097153;
static constexpr long long OFF_ENC  = 2097154;            // float idx % 4 == 2 -> region 8B aligned; enc+2 is 16B aligned
static constexpr long long OFF_DIST = 2097154LL + 33554432LL; // same alignment situation

// ws layout: [0,4096) int counts[1024]; [4096,8192) float ww[1024];
//            [8192,8196) float lossSum; [12288, 12288+256K) float WT[64][1024]

#define AS1 __attribute__((address_space(1)))
#define AS3 __attribute__((address_space(3)))

typedef float __attribute__((ext_vector_type(2))) f32x2;
typedef float __attribute__((ext_vector_type(4))) f32x4;

// Non-temporal (L2-bypass hint) streaming stores: the 256 MB of one-touch
// enc/dist/Q writes must not evict the WT panel from L2 (R5 counters: main's
// write BW 2.3 TB/s vs fill 5.5 TB/s; FETCH 7x input size = L2 thrash).
__device__ __forceinline__ void ntstore2(float* p, float a, float b) {
    f32x2 v = {a, b};
    __builtin_nontemporal_store(v, (f32x2*)p);
}
__device__ __forceinline__ void ntstore4z(float* p) {
    f32x4 v = {0.f, 0.f, 0.f, 0.f};
    __builtin_nontemporal_store(v, (f32x4*)p);
}
__device__ __forceinline__ void ntstore4(float* p, float a, float b, float c, float d) {
    f32x4 v = {a, b, c, d};
    __builtin_nontemporal_store(v, (f32x4*)p);
}

// Direct global->LDS DMA, 16B per lane. LDS dest must be wave-uniform base;
// HW writes lane i's 16B at base + i*16. Global src is per-lane.
__device__ __forceinline__ void gld16(const float* g, float* l) {
    __builtin_amdgcn_global_load_lds((const AS1 unsigned int*)g,
                                     (AS3 unsigned int*)l, 16, 0, 0);
}

// Counted-vmcnt phase barrier: wait until <=N VMEM ops outstanding (in-order
// FIFO -> guarantees everything older than the N youngest has retired), then
// raw workgroup barrier. sched_barrier(0) pins code motion across it.
#define PHASE_SYNC(N) do {                                        \
    asm volatile("s_waitcnt vmcnt(" #N ")" ::: "memory");         \
    __builtin_amdgcn_s_barrier();                                 \
    __builtin_amdgcn_sched_barrier(0);                            \
} while (0)

// ---------------------------------------------------------------------------
// Prep: ||w_k||^2 (blocks 0..255) + W transpose WT[n][k] (blocks 256..319)
//     + enc row-boundary zero patches (blocks 320..383)
//     + counts/lossSum zeroing (block 384).
__global__ __launch_bounds__(256) void vq_prep_kernel(const float* __restrict__ W,
                                                      float* __restrict__ ww,
                                                      float* __restrict__ WT,
                                                      float* __restrict__ out,
                                                      int* __restrict__ counts,
                                                      float* __restrict__ lossSum) {
    const int tid = threadIdx.x;
    const int b   = blockIdx.x;
    if (b < 256) {
        const int lane = tid & 63;
        const int code = b * 4 + (tid >> 6);
        float v = W[code * DIM + lane];
        float s = v * v;
        #pragma unroll
        for (int off = 32; off > 0; off >>= 1)
            s += __shfl_down(s, off, 64);
        if (lane == 0) ww[code] = s;
    } else if (b < 320) {
        const int n = b - 256;            // 0..63
        #pragma unroll
        for (int i = 0; i < 4; ++i) {
            int k = i * 256 + tid;
            WT[n * KCODES + k] = W[k * DIM + n];
        }
    } else if (b < 384) {
        // enc boundary patches: floats {0,1} and {1022,1023} of every row
        // (main's in-loop streaming covers the 16B-aligned interior [2,1022)).
        float* __restrict__ enc = out + OFF_ENC;
        const int r0 = (b - 320) * 512 + tid * 2;   // 2 rows per thread
        const long long rb = (long long)r0 * KCODES;
        ntstore2(&enc[rb], 0.f, 0.f);
        ntstore2(&enc[rb + 1022], 0.f, 0.f);
        ntstore2(&enc[rb + 1024], 0.f, 0.f);
        ntstore2(&enc[rb + 1024 + 1022], 0.f, 0.f);
    } else {
        #pragma unroll
        for (int i = 0; i < 4; ++i) counts[i * 256 + tid] = 0;
        if (tid == 0) lossSum[0] = 0.f;
    }
}

// ---------------------------------------------------------------------------
// Main fused kernel: distances GEMM + argmin + one-hot + gather + loss partial.
// 512 blocks x 256 threads; each block owns 64 consecutive flat rows t.
// 16 pipelined phases (2 code-chunks x 8 n-slices of 8), double-buffered LDS
// staged via global_load_lds, counted-vmcnt barriers (stores never drained
// in-loop), NON-TEMPORAL streaming stores (enc/dist/Q bypass L2 so the WT
// panel stays L2-resident for the per-phase prefetches).
// Per-phase VMEM issue order (uniform across waves): 4x gld16 -> 4x enc f4
// -> [q==7: 64x dist f2].
__global__ __launch_bounds__(256, 2) void vq_main_kernel(const float* __restrict__ lat,
                                                         const float* __restrict__ W,
                                                         const float* __restrict__ ww,
                                                         const float* __restrict__ WT,
                                                         float* __restrict__ out,
                                                         int* __restrict__ counts,
                                                         float* __restrict__ lossSum) {
    __shared__ float xT[64 * 64];      // [n][tl] 16 KB — persistent across kernel
    __shared__ float wS[2][8 * 512];   // [nl][k] 16 KB x2 double buffer; reused for red/qS
    __shared__ float wwS[KCODES];      // ||w||^2, 4 KB
    __shared__ float xx[64];           // ||x_row||^2
    __shared__ int   selIdx[64];

    const int tid = threadIdx.x;
    const int tx  = tid & 31;          // 32 k-threads x 16 codes = 512-code chunk
    const int ty  = tid >> 5;          // 8 row-groups
    const int t0  = blockIdx.x * 64;
    // flat row t maps to latent addr b*65536 + n*1024 + (j*32+d); for a 64-row block
    // the (j*32+d) part is contiguous: base + n*1024 + tl
    const long long base = (long long)(t0 >> 10) * 65536 + (long long)(t0 & 1023);
    const int wbase = (tid & 192) * 4; // wave-uniform float-offset component of LDS dest

    // ---- prologue: DMA x tile (16 KB) + first WT slice (16 KB) straight into LDS
    #pragma unroll
    for (int i = 0; i < 4; ++i) {
        const int e = i * 256 + tid;   // f4 index in [0,1024)
        gld16(&lat[base + (long long)(e >> 4) * 1024 + (e & 15) * 4],
              &xT[i * 1024 + wbase]);
    }
    #pragma unroll
    for (int i = 0; i < 4; ++i) {
        const int e = i * 256 + tid;   // f4 index in [0,1024): nl = e>>7, k4 = e&127
        gld16(&WT[(e >> 7) * KCODES + (e & 127) * 4],
              &wS[0][i * 1024 + wbase]);
    }
    *(float4*)&wwS[tid * 4] = *(const float4*)&ww[tid * 4];
    __syncthreads();                   // full drain: vmcnt=0 entering the loop

    // ||x||^2 per row (wave 0 only; published by the phase-0 end barrier,
    // first consumed at phase 7)
    if (tid < 64) {
        float s = 0.f;
        #pragma unroll 8
        for (int n = 0; n < 64; ++n) {
            float v = xT[n * 64 + tid];
            s = fmaf(v, v, s);
        }
        xx[tid] = s;
    }

    float minV[8];
    int   minI[8];
    #pragma unroll
    for (int r = 0; r < 8; ++r) { minV[r] = FLT_MAX; minI[r] = 0; }

    float acc[8][16];
    float* __restrict__ distOut = out + OFF_DIST;
    float* __restrict__ enc     = out + OFF_ENC;
    const int tcl = (tid < 255 ? tid : 254) * 4;   // tail thread duplicates slot 254
                                                   // (same-address zero store, benign)
                                                   // -> uniform 4 stores per thread

    for (int p = 0; p < 16; ++p) {     // phase p = c*8 + q: codes [c*512,(c+1)*512), dims [q*8,q*8+8)
        const int c   = p >> 3;
        const int q   = p & 7;
        const int buf = p & 1;

        // ---- (1) prefetch next phase's WT slice — the ONLY loads this phase;
        //      issued first so they are the OLDEST VMEM ops at the barrier.
        if (p < 15) {
            const int pn = p + 1;
            const float* srcb = WT + (pn & 7) * (8 * KCODES) + (pn >> 3) * 512;
            float* dstb = &wS[pn & 1][0];
            #pragma unroll
            for (int i = 0; i < 4; ++i) {
                const int e = i * 256 + tid;
                gld16(&srcb[(e >> 7) * KCODES + (e & 127) * 4],
                      &dstb[i * 1024 + wbase]);
            }
        }
        asm volatile("" ::: "memory"); // pin: all loads precede all stores

        // ---- (2) enc zero-fill interior [2,1022) for rows p*4..p*4+3
        //      (uniform 4 nt float4 stores/thread; boundaries written by prep)
        {
            float* pz = enc + (long long)(t0 + p * 4) * KCODES + 2;
            ntstore4z(pz + tcl);
            ntstore4z(pz + 1024 + tcl);
            ntstore4z(pz + 2048 + tcl);
            ntstore4z(pz + 3072 + tcl);
        }

        if (q == 0) {
            #pragma unroll
            for (int r = 0; r < 8; ++r)
                #pragma unroll
                for (int k = 0; k < 16; ++k) acc[r][k] = 0.f;
        }

        // ---- (3) 8x16 register-tiled fp32 GEMM over this 8-dim slice
        #pragma unroll 2
        for (int nn = 0; nn < 8; ++nn) {
            const float* xrow = &xT[(q * 8 + nn) * 64];
            const float* wrow = &wS[buf][nn * 512];
            float4 a0 = *(const float4*)&xrow[ty * 4];        // broadcast (free)
            float4 a1 = *(const float4*)&xrow[32 + ty * 4];
            float4 b0 = *(const float4*)&wrow[tx * 4];        // contiguous b128
            float4 b1 = *(const float4*)&wrow[128 + tx * 4];
            float4 b2 = *(const float4*)&wrow[256 + tx * 4];
            float4 b3 = *(const float4*)&wrow[384 + tx * 4];
            float ar[8]  = {a0.x, a0.y, a0.z, a0.w, a1.x, a1.y, a1.z, a1.w};
            float br[16] = {b0.x, b0.y, b0.z, b0.w, b1.x, b1.y, b1.z, b1.w,
                            b2.x, b2.y, b2.z, b2.w, b3.x, b3.y, b3.z, b3.w};
            #pragma unroll
            for (int r = 0; r < 8; ++r)
                #pragma unroll
                for (int k = 0; k < 16; ++k)
                    acc[r][k] = fmaf(ar[r], br[k], acc[r][k]);
        }

        // ---- (4) chunk complete: distances out (nt) + running argmin
        // thread's codes: k = c*512 + qq*128 + tx*4 + j — ascending scan order,
        // strict < keeps the first (np.argmin tie semantics)
        if (q == 7) {
            const int kb = c * 512 + tx * 4;
            float wr[16];
            #pragma unroll
            for (int qq = 0; qq < 4; ++qq) {
                float4 w4 = *(const float4*)&wwS[kb + qq * 128];
                wr[qq*4+0] = w4.x; wr[qq*4+1] = w4.y; wr[qq*4+2] = w4.z; wr[qq*4+3] = w4.w;
            }
            #pragma unroll
            for (int r = 0; r < 8; ++r) {
                const int row = (r >> 2) * 32 + ty * 4 + (r & 3);
                const float xxr = xx[row];
                const long long ro = (long long)(t0 + row) * KCODES + kb;
                #pragma unroll
                for (int qq = 0; qq < 4; ++qq) {
                    float d0 = (xxr + wr[qq*4+0]) - 2.f * acc[r][qq*4+0];
                    float d1 = (xxr + wr[qq*4+1]) - 2.f * acc[r][qq*4+1];
                    float d2 = (xxr + wr[qq*4+2]) - 2.f * acc[r][qq*4+2];
                    float d3 = (xxr + wr[qq*4+3]) - 2.f * acc[r][qq*4+3];
                    const int k0 = kb + qq * 128;
                    if (d0 < minV[r]) { minV[r] = d0; minI[r] = k0;     }
                    if (d1 < minV[r]) { minV[r] = d1; minI[r] = k0 + 1; }
                    if (d2 < minV[r]) { minV[r] = d2; minI[r] = k0 + 2; }
                    if (d3 < minV[r]) { minV[r] = d3; minI[r] = k0 + 3; }
                    ntstore2(&distOut[ro + qq * 128],     d0, d1);
                    ntstore2(&distOut[ro + qq * 128 + 2], d2, d3);
                }
            }
        }

        // ---- (5) counted-vmcnt barrier: wait ONLY for this phase's 4 prefetch
        // loads (oldest in the FIFO); leave the store burst in flight. vmcnt
        // field max is 63, so q==7 uses 63 (68 outstanding -> retires the 4
        // loads + 1 store). Older leftovers are implicitly forced out by the
        // in-order count at the next phase's wait.
        if (q == 7) PHASE_SYNC(63);
        else        PHASE_SYNC(4);
    }

    // ---- cross-thread argmin reduction (32 candidates per row), alias wS
    // (phase-15 barrier guaranteed all GEMM reads of wS retired; phase 15
    // reads wS[1], redV aliases wS[0] — no prefetch wrote it at p=15)
    float* wSf  = &wS[0][0];
    float* redV = wSf;                 // [64][33] padded -> conflict-free scan
    int*   redI = (int*)(wSf + 64 * 33);
    #pragma unroll
    for (int r = 0; r < 8; ++r) {
        const int row = (r >> 2) * 32 + ty * 4 + (r & 3);
        redV[row * 33 + tx] = minV[r];
        redI[row * 33 + tx] = minI[r];
    }
    __syncthreads();                   // FULL drain: retires all in-flight stores
                                       // (required before the enc 1.0 fixups below)
    if (tid < 64) {
        float best = redV[tid * 33];
        int   bi   = redI[tid * 33];
        #pragma unroll
        for (int s = 1; s < 32; ++s) {
            float v  = redV[tid * 33 + s];
            int   i2 = redI[tid * 33 + s];
            if (v < best || (v == best && i2 < bi)) { best = v; bi = i2; }
        }
        selIdx[tid] = bi;
        atomicAdd(&counts[bi], 1);
    }
    __syncthreads();

    // ---- gather selected codebook rows into LDS (coalesced), stride 65 kills conflicts
    float* qS = wSf;  // reuse (scan done)
    #pragma unroll
    for (int i = 0; i < 16; ++i) {
        int e   = i * 256 + tid;
        int row = e >> 6;
        int n   = e & 63;
        qS[row * 65 + n] = W[selIdx[row] * DIM + n];
    }
    __syncthreads();

    // ---- quantized_out (nt float4, 16B aligned) + loss partial
    float ls = 0.f;
    #pragma unroll
    for (int i = 0; i < 4; ++i) {
        int e2  = i * 256 + tid;       // [0,1024) float4s
        int n   = e2 >> 4;
        int tl0 = (e2 & 15) * 4;
        float q0 = qS[(tl0 + 0) * 65 + n];
        float q1 = qS[(tl0 + 1) * 65 + n];
        float q2 = qS[(tl0 + 2) * 65 + n];
        float q3 = qS[(tl0 + 3) * 65 + n];
        float x0 = xT[n * 64 + tl0 + 0];
        float x1 = xT[n * 64 + tl0 + 1];
        float x2 = xT[n * 64 + tl0 + 2];
        float x3 = xT[n * 64 + tl0 + 3];
        ntstore4(&out[OFF_Q + base + (long long)n * 1024 + tl0], q0, q1, q2, q3);
        float e0 = q0 - x0; ls = fmaf(e0, e0, ls);
        float e1 = q1 - x1; ls = fmaf(e1, e1, ls);
        float e2d = q2 - x2; ls = fmaf(e2d, e2d, ls);
        float e3 = q3 - x3; ls = fmaf(e3, e3, ls);
    }
    #pragma unroll
    for (int off = 32; off > 0; off >>= 1)
        ls += __shfl_down(ls, off, 64);
    if ((tid & 63) == 0) atomicAdd(lossSum, ls);

    // ---- one-hot fix-up: zeros (interior from the loop, boundaries from prep)
    // are all drained by the epilogue's first __syncthreads, so a single 1.0
    // store per row completes encodings (normal store: read-modify of the
    // already-retired zeroed line is coherent at device scope).
    if (tid < 64)
        enc[(long long)(t0 + tid) * KCODES + selIdx[tid]] = 1.f;
}

// ---------------------------------------------------------------------------
// Finalize: perplexity from histogram, loss from accumulated SSE.
__global__ __launch_bounds__(1024) void vq_finalize_kernel(const int* __restrict__ counts,
                                                           const float* __restrict__ lossSum,
                                                           float* __restrict__ out) {
    __shared__ float red[16];
    const int tid = threadIdx.x;
    float p = (float)counts[tid] * (1.0f / 32768.0f);   // exact (pow2 divisor)
    float term = p * logf(p + 1e-10f);
    #pragma unroll
    for (int off = 32; off > 0; off >>= 1)
        term += __shfl_down(term, off, 64);
    if ((tid & 63) == 0) red[tid >> 6] = term;
    __syncthreads();
    if (tid == 0) {
        float s = 0.f;
        #pragma unroll
        for (int i = 0; i < 16; ++i) s += red[i];
        out[OFF_PERP] = expf(-s);
        out[OFF_LOSS] = 0.25f * lossSum[0] * (1.0f / 2097152.0f);  // COMMIT_COST * mean SSE
    }
}

// ---------------------------------------------------------------------------
extern "C" void kernel_launch(void* const* d_in, const int* in_sizes, int n_in,
                              void* d_out, int out_size, void* d_ws, size_t ws_size,
                              hipStream_t stream) {
    (void)in_sizes; (void)n_in; (void)out_size; (void)ws_size;
    const float* lat = (const float*)d_in[0];   // [32,64,32,32]
    const float* W   = (const float*)d_in[1];   // [1024,64]
    float* out = (float*)d_out;

    int*   counts  = (int*)d_ws;
    float* ww      = (float*)((char*)d_ws + 4096);
    float* lossSum = (float*)((char*)d_ws + 8192);
    float* WT      = (float*)((char*)d_ws + 12288);   // 64x1024 fp32 = 256 KB

    // prep zeroes counts/lossSum (block 384) — no hipMemsetAsync dispatch needed
    vq_prep_kernel<<<385, 256, 0, stream>>>(W, ww, WT, out, counts, lossSum);
    vq_main_kernel<<<512, 256, 0, stream>>>(lat, W, ww, WT, out, counts, lossSum);
    vq_finalize_kernel<<<1, 1024, 0, stream>>>(counts, lossSum, out);
}